// Round 8
// baseline (398.917 us; speedup 1.0000x reference)
//
#include <hip/hip_runtime.h>
#include <hip/hip_fp16.h>
#include <cstdint>

typedef _Float16 f16x8 __attribute__((ext_vector_type(8)));
typedef float f32x4 __attribute__((ext_vector_type(4)));

// ---------------- graph preprocessing ----------------

__global__ __launch_bounds__(256) void k_count(const int* __restrict__ dst, int* __restrict__ cnt, int E) {
    int e = blockIdx.x * 256 + threadIdx.x;
    if (e < E) atomicAdd(&cnt[dst[e]], 1);
}

// per-4096-chunk sums of cnt
__global__ __launch_bounds__(256) void k_scan_sum(const int* __restrict__ cnt, int* __restrict__ bsum, int N) {
    int base = blockIdx.x * 4096 + threadIdx.x * 16;
    int s = 0;
    if (base + 16 <= N) {
        const int4* p = (const int4*)(cnt + base);
        int4 a = p[0], b = p[1], c = p[2], d = p[3];
        s = a.x + a.y + a.z + a.w + b.x + b.y + b.z + b.w
          + c.x + c.y + c.z + c.w + d.x + d.y + d.z + d.w;
    } else {
        for (int i = base; i < N; i++) s += cnt[i];
    }
    __shared__ int ws[4];
#pragma unroll
    for (int off = 32; off; off >>= 1) s += __shfl_down(s, off, 64);
    if ((threadIdx.x & 63) == 0) ws[threadIdx.x >> 6] = s;
    __syncthreads();
    if (threadIdx.x == 0) bsum[blockIdx.x] = ws[0] + ws[1] + ws[2] + ws[3];
}

// exclusive scan apply + rowstart[N] + dinv, fused
__global__ __launch_bounds__(256) void k_scan_apply(const int* __restrict__ cnt, const int* __restrict__ bsum,
                                                    int* __restrict__ rowstart, float* __restrict__ dinv,
                                                    int N, int SB) {
    __shared__ int boff_s;
    __shared__ int ls[256];
    int t = threadIdx.x;
    if (t == 0) {
        int run = 0;
        for (int i = 0; i < (int)blockIdx.x; i++) run += bsum[i];
        boff_s = run;
        if ((int)blockIdx.x == SB - 1) {
            int tot = run;
            for (int i = blockIdx.x; i < SB; i++) tot += bsum[i];
            rowstart[N] = tot;
        }
    }
    int base = blockIdx.x * 4096 + t * 16;
    int v[16], e[16];
    int s = 0;
    bool full = (base + 16 <= N);
    if (full) {
        const int4* p = (const int4*)(cnt + base);
        int4 q0 = p[0], q1 = p[1], q2 = p[2], q3 = p[3];
        int tmp[16] = {q0.x, q0.y, q0.z, q0.w, q1.x, q1.y, q1.z, q1.w,
                       q2.x, q2.y, q2.z, q2.w, q3.x, q3.y, q3.z, q3.w};
#pragma unroll
        for (int j = 0; j < 16; j++) { e[j] = tmp[j]; v[j] = s; s += e[j]; }
    } else {
#pragma unroll
        for (int j = 0; j < 16; j++) { int i = base + j; e[j] = (i < N) ? cnt[i] : 0; v[j] = s; s += e[j]; }
    }
    ls[t] = s;
    __syncthreads();
    for (int off = 1; off < 256; off <<= 1) {
        int o = (t >= off) ? ls[t - off] : 0;
        __syncthreads();
        ls[t] += o;
        __syncthreads();
    }
    int excl = ls[t] - s + boff_s;
    if (full) {
        int w[16];
        float dv[16];
#pragma unroll
        for (int j = 0; j < 16; j++) { w[j] = v[j] + excl; dv[j] = rsqrtf((float)(e[j] + 1)); }
        int4* p = (int4*)(rowstart + base);
        p[0] = make_int4(w[0], w[1], w[2], w[3]);
        p[1] = make_int4(w[4], w[5], w[6], w[7]);
        p[2] = make_int4(w[8], w[9], w[10], w[11]);
        p[3] = make_int4(w[12], w[13], w[14], w[15]);
        float4* q = (float4*)(dinv + base);
        q[0] = make_float4(dv[0], dv[1], dv[2], dv[3]);
        q[1] = make_float4(dv[4], dv[5], dv[6], dv[7]);
        q[2] = make_float4(dv[8], dv[9], dv[10], dv[11]);
        q[3] = make_float4(dv[12], dv[13], dv[14], dv[15]);
    } else {
        for (int j = 0; j < 16; j++) {
            int i = base + j;
            if (i < N) { rowstart[i] = v[j] + excl; dinv[i] = rsqrtf((float)(e[j] + 1)); }
        }
    }
}

// ---- two-phase binned scatter: bucket = 32-node range, CSR-contiguous ----

// phase 1: edge -> tmp[bucket region], payload (dst, src)
__global__ __launch_bounds__(256) void k_bin(const int* __restrict__ src, const int* __restrict__ dst,
                                             const int* __restrict__ rowstart, int* __restrict__ bcur,
                                             int2* __restrict__ tmp, int E) {
    int e = blockIdx.x * 256 + threadIdx.x;
    if (e >= E) return;
    int d = dst[e];
    int b = d >> 5;
    int pos = rowstart[b << 5] + atomicAdd(&bcur[b], 1);
    tmp[pos] = make_int2(d, src[e]);
}

// phase 2: one block per bucket; LDS rowstart window + LDS cursors; local csr writes
__global__ __launch_bounds__(256) void k_scatter_local(const int2* __restrict__ tmp, const int* __restrict__ rowstart,
                                                       int* __restrict__ csr, int N) {
    __shared__ int lcur[32];
    __shared__ int rw[33];
    int lo = blockIdx.x << 5;
    int nn = min(32, N - lo);
    int t = threadIdx.x;
    if (t < 32) lcur[t] = 0;
    if (t < nn + 1) rw[t] = rowstart[lo + t];
    __syncthreads();
    int e0 = rw[0], e1 = rw[nn];
    for (int i = e0 + t; i < e1; i += 256) {
        int2 p = tmp[i];
        int pos = rw[p.x - lo] + atomicAdd(&lcur[p.x - lo], 1);
        csr[pos] = p.y;
    }
}

// ---------------- weight transposes (all 3 in one launch) ----------------

__global__ __launch_bounds__(256) void k_wt_all(const float* __restrict__ W0, const float* __restrict__ W1,
                                                const float* __restrict__ W2,
                                                __half* __restrict__ W0t, __half* __restrict__ W1t,
                                                __half* __restrict__ W2t, int DOUT) {
    int idx = blockIdx.x * 256 + threadIdx.x;
    if (idx < 16384) {
        int c = idx >> 7, k = idx & 127;
        W0t[idx] = __float2half(W0[k * 128 + c]);
    } else if (idx < 32768) {
        int i = idx - 16384;
        int c = i >> 7, k = i & 127;
        W1t[i] = __float2half(W1[k * 128 + c]);
    } else if (idx < 32768 + 48 * 128) {
        int i = idx - 32768;
        int c = i >> 7, k = i & 127;
        W2t[i] = (c < DOUT) ? __float2half(W2[k * DOUT + c]) : __half(0);
    }
}

// ---------------- dtype helpers ----------------

__device__ inline void store1f(float* p, float v) { *p = v; }
__device__ inline void store1f(__half* p, float v) { *p = __float2half(v); }

__device__ inline f16x8 load_a8(const __half* p) { return *(const f16x8*)p; }
__device__ inline f16x8 load_a8(const float* p) {
    float4 a = *(const float4*)p;
    float4 b = *(const float4*)(p + 4);
    f16x8 r;
    r[0] = (_Float16)a.x; r[1] = (_Float16)a.y; r[2] = (_Float16)a.z; r[3] = (_Float16)a.w;
    r[4] = (_Float16)b.x; r[5] = (_Float16)b.y; r[6] = (_Float16)b.z; r[7] = (_Float16)b.w;
    return r;
}

// ---------------- MFMA GEMM ----------------

template<int CT, typename InT, typename OutT>
__global__ __launch_bounds__(256) void k_gemm_mfma(const InT* __restrict__ A,
                                                   const __half* __restrict__ Wt,
                                                   const float* __restrict__ sums,
                                                   const float* __restrict__ g,
                                                   const float* __restrict__ bt,
                                                   float invN,
                                                   const float* __restrict__ dscale,
                                                   OutT* __restrict__ C, int M, int NC) {
    int lane = threadIdx.x & 63;
    int r0 = blockIdx.x * 64 + (threadIdx.x >> 6) * 16;
    if (r0 >= M) return;
    int lrow = lane & 15;
    int lk = (lane >> 4) << 3;

    f16x8 b[CT][4];
#pragma unroll
    for (int c = 0; c < CT; c++)
#pragma unroll
        for (int kt = 0; kt < 4; kt++)
            b[c][kt] = *(const f16x8*)(Wt + (size_t)(c * 16 + lrow) * 128 + kt * 32 + lk);

    f32x4 acc[CT];
#pragma unroll
    for (int c = 0; c < CT; c++) acc[c] = f32x4{0.f, 0.f, 0.f, 0.f};

    int row = r0 + lrow;
    bool rv = (row < M);
    const InT* Arow = A + (size_t)(rv ? row : 0) * 128 + lk;

#pragma unroll
    for (int kt = 0; kt < 4; kt++) {
        f16x8 a = load_a8(Arow + kt * 32);
        if (!rv) a = f16x8{};
        if (sums) {
            int ch = kt * 32 + lk;
            float4 s1a = *(const float4*)(sums + ch);
            float4 s1b = *(const float4*)(sums + ch + 4);
            float4 s2a = *(const float4*)(sums + 128 + ch);
            float4 s2b = *(const float4*)(sums + 128 + ch + 4);
            float4 ga  = *(const float4*)(g + ch);
            float4 gb  = *(const float4*)(g + ch + 4);
            float4 ba  = *(const float4*)(bt + ch);
            float4 bb  = *(const float4*)(bt + ch + 4);
            float s1v[8] = {s1a.x, s1a.y, s1a.z, s1a.w, s1b.x, s1b.y, s1b.z, s1b.w};
            float s2v[8] = {s2a.x, s2a.y, s2a.z, s2a.w, s2b.x, s2b.y, s2b.z, s2b.w};
            float gv[8]  = {ga.x, ga.y, ga.z, ga.w, gb.x, gb.y, gb.z, gb.w};
            float btv[8] = {ba.x, ba.y, ba.z, ba.w, bb.x, bb.y, bb.z, bb.w};
#pragma unroll
            for (int j = 0; j < 8; j++) {
                float mu  = s1v[j] * invN;
                float var = s2v[j] * invN - mu * mu;
                float w   = rsqrtf(var + 1e-5f) * gv[j];
                float sh  = btv[j] - mu * w;
                a[j] = (_Float16)fmaxf(fmaf((float)a[j], w, sh), 0.f);
            }
        }
#pragma unroll
        for (int c = 0; c < CT; c++)
            acc[c] = __builtin_amdgcn_mfma_f32_16x16x32_f16(a, b[c][kt], acc[c], 0, 0, 0);
    }

    int rbase = r0 + ((lane >> 4) << 2);
    float4 ds4 = *(const float4*)(dscale + rbase);
    float dsv[4] = {ds4.x, ds4.y, ds4.z, ds4.w};
#pragma unroll
    for (int c = 0; c < CT; c++) {
        int col = c * 16 + lrow;
        if (col >= NC) continue;
#pragma unroll
        for (int reg = 0; reg < 4; reg++) {
            int r = rbase + reg;
            if (r < M) store1f(C + (size_t)r * NC + col, acc[c][reg] * dsv[reg]);
        }
    }
}

// ---------------- aggregation, fp16 gather (D=128), fp16 out ----------------

__device__ inline void acc_h4(float2 raw, float& ax, float& ay, float& az, float& aw) {
    union { float f; __half2 h; } u0, u1;
    u0.f = raw.x; u1.f = raw.y;
    float2 f01 = __half22float2(u0.h);
    float2 f23 = __half22float2(u1.h);
    ax += f01.x; ay += f01.y; az += f23.x; aw += f23.y;
}

__global__ __launch_bounds__(256) void k_aggregate_h(const __half* __restrict__ Hs, const int* __restrict__ csr,
                                                     const int* __restrict__ rowstart, const float* __restrict__ dinv,
                                                     const float* __restrict__ bias, __half* __restrict__ out, int N) {
    int node = blockIdx.x * 8 + (threadIdx.x >> 5);
    int lane = threadIdx.x & 31;
    int c = lane << 2;
    if (node >= N) return;

    int s0 = rowstart[node], s1 = rowstart[node + 1];
    float ax = 0.f, ay = 0.f, az = 0.f, aw = 0.f;

    int j = s0;
    for (; j + 8 <= s1; j += 8) {
        int i0 = csr[j + 0], i1 = csr[j + 1], i2 = csr[j + 2], i3 = csr[j + 3];
        int i4 = csr[j + 4], i5 = csr[j + 5], i6 = csr[j + 6], i7 = csr[j + 7];
        float2 r0 = *(const float2*)(Hs + (size_t)i0 * 128 + c);
        float2 r1 = *(const float2*)(Hs + (size_t)i1 * 128 + c);
        float2 r2 = *(const float2*)(Hs + (size_t)i2 * 128 + c);
        float2 r3 = *(const float2*)(Hs + (size_t)i3 * 128 + c);
        float2 r4 = *(const float2*)(Hs + (size_t)i4 * 128 + c);
        float2 r5 = *(const float2*)(Hs + (size_t)i5 * 128 + c);
        float2 r6 = *(const float2*)(Hs + (size_t)i6 * 128 + c);
        float2 r7 = *(const float2*)(Hs + (size_t)i7 * 128 + c);
        acc_h4(r0, ax, ay, az, aw); acc_h4(r1, ax, ay, az, aw);
        acc_h4(r2, ax, ay, az, aw); acc_h4(r3, ax, ay, az, aw);
        acc_h4(r4, ax, ay, az, aw); acc_h4(r5, ax, ay, az, aw);
        acc_h4(r6, ax, ay, az, aw); acc_h4(r7, ax, ay, az, aw);
    }
    for (; j < s1; j++) {
        int s = csr[j];
        float2 r = *(const float2*)(Hs + (size_t)s * 128 + c);
        acc_h4(r, ax, ay, az, aw);
    }

    float2 rs = *(const float2*)(Hs + (size_t)node * 128 + c);
    acc_h4(rs, ax, ay, az, aw);

    float dn = dinv[node];
    float4 b4 = *(const float4*)(bias + c);
    union { __half2 h[2]; float2 f; } u;
    u.h[0] = __floats2half2_rn(ax * dn + b4.x, ay * dn + b4.y);
    u.h[1] = __floats2half2_rn(az * dn + b4.z, aw * dn + b4.w);
    *(float2*)(out + (size_t)node * 128 + c) = u.f;
}

// ---------------- aggregation + log_softmax, fp32 (layer 3, D<=64) ----------------

__global__ __launch_bounds__(256) void k_aggregate_lsm(const float* __restrict__ Hs, const int* __restrict__ csr,
                                                       const int* __restrict__ rowstart, const float* __restrict__ dinv,
                                                       const float* __restrict__ bias, float* __restrict__ out,
                                                       int N, int D) {
    int node = blockIdx.x * 16 + (threadIdx.x >> 4);
    int lane = threadIdx.x & 15;
    int c = lane << 2;
    if (node >= N) return;
    bool act = c < D;

    int s0 = rowstart[node], s1 = rowstart[node + 1];
    float ax = 0.f, ay = 0.f, az = 0.f, aw = 0.f;

    int j = s0;
    for (; j + 8 <= s1; j += 8) {
        int i0 = csr[j + 0], i1 = csr[j + 1], i2 = csr[j + 2], i3 = csr[j + 3];
        int i4 = csr[j + 4], i5 = csr[j + 5], i6 = csr[j + 6], i7 = csr[j + 7];
        if (act) {
            float4 v0 = *(const float4*)(Hs + (size_t)i0 * D + c);
            float4 v1 = *(const float4*)(Hs + (size_t)i1 * D + c);
            float4 v2 = *(const float4*)(Hs + (size_t)i2 * D + c);
            float4 v3 = *(const float4*)(Hs + (size_t)i3 * D + c);
            float4 v4 = *(const float4*)(Hs + (size_t)i4 * D + c);
            float4 v5 = *(const float4*)(Hs + (size_t)i5 * D + c);
            float4 v6 = *(const float4*)(Hs + (size_t)i6 * D + c);
            float4 v7 = *(const float4*)(Hs + (size_t)i7 * D + c);
            ax += v0.x; ay += v0.y; az += v0.z; aw += v0.w;
            ax += v1.x; ay += v1.y; az += v1.z; aw += v1.w;
            ax += v2.x; ay += v2.y; az += v2.z; aw += v2.w;
            ax += v3.x; ay += v3.y; az += v3.z; aw += v3.w;
            ax += v4.x; ay += v4.y; az += v4.z; aw += v4.w;
            ax += v5.x; ay += v5.y; az += v5.z; aw += v5.w;
            ax += v6.x; ay += v6.y; az += v6.z; aw += v6.w;
            ax += v7.x; ay += v7.y; az += v7.z; aw += v7.w;
        }
    }
    for (; j < s1; j++) {
        int s = csr[j];
        if (act) {
            float4 v = *(const float4*)(Hs + (size_t)s * D + c);
            ax += v.x; ay += v.y; az += v.z; aw += v.w;
        }
    }

    float4 r = make_float4(0.f, 0.f, 0.f, 0.f);
    if (act) {
        float4 self = *(const float4*)(Hs + (size_t)node * D + c);
        float dn = dinv[node];
        float4 b4 = *(const float4*)(bias + c);
        r.x = (ax + self.x) * dn + b4.x;
        r.y = (ay + self.y) * dn + b4.y;
        r.z = (az + self.z) * dn + b4.z;
        r.w = (aw + self.w) * dn + b4.w;
    }

    float m = act ? fmaxf(fmaxf(r.x, r.y), fmaxf(r.z, r.w)) : -1e30f;
#pragma unroll
    for (int off = 8; off; off >>= 1) m = fmaxf(m, __shfl_xor(m, off, 16));
    float es = act ? (expf(r.x - m) + expf(r.y - m) + expf(r.z - m) + expf(r.w - m)) : 0.f;
#pragma unroll
    for (int off = 8; off; off >>= 1) es += __shfl_xor(es, off, 16);
    float ls = logf(es);
    if (act) {
        float4 o = make_float4(r.x - m - ls, r.y - m - ls, r.z - m - ls, r.w - m - ls);
        *(float4*)(out + (size_t)node * D + c) = o;
    }
}

// ---------------- BatchNorm stats (fp16 input) ----------------

__global__ __launch_bounds__(256) void k_bn_stats_h(const __half* __restrict__ H, float* __restrict__ sums, int N) {
    __shared__ float ls[256], ls2[256];
    int c = threadIdx.x & 127;
    int half = threadIdx.x >> 7;
    float s = 0.f, s2 = 0.f;
    for (int r = blockIdx.x * 2 + half; r < N; r += gridDim.x * 2) {
        float v = __half2float(H[(size_t)r * 128 + c]);
        s += v; s2 += v * v;
    }
    ls[threadIdx.x] = s; ls2[threadIdx.x] = s2;
    __syncthreads();
    if (threadIdx.x < 128) {
        atomicAdd(&sums[c], ls[threadIdx.x] + ls[threadIdx.x + 128]);
        atomicAdd(&sums[128 + c], ls2[threadIdx.x] + ls2[threadIdx.x + 128]);
    }
}

// ---------------- launch ----------------

extern "C" void kernel_launch(void* const* d_in, const int* in_sizes, int n_in,
                              void* d_out, int out_size, void* d_ws, size_t ws_size,
                              hipStream_t stream) {
    const float* x   = (const float*)d_in[0];
    const int*   ei  = (const int*)d_in[1];
    const float* W0  = (const float*)d_in[2];
    const float* b0  = (const float*)d_in[3];
    const float* W1  = (const float*)d_in[4];
    const float* b1  = (const float*)d_in[5];
    const float* W2  = (const float*)d_in[6];
    const float* b2  = (const float*)d_in[7];
    const float* g0  = (const float*)d_in[8];
    const float* bt0 = (const float*)d_in[9];
    const float* g1  = (const float*)d_in[10];
    const float* bt1 = (const float*)d_in[11];
    float* out = (float*)d_out;

    int N    = in_sizes[0] / 128;
    int E    = in_sizes[1] / 2;
    int DOUT = in_sizes[7];          // 40
    float invN = 1.0f / (float)N;

    const int* srcp = ei;
    const int* dstp = ei + E;

    int NB = (N + 31) / 32;          // scatter buckets (32 nodes each)

    size_t off = 0;
    auto carve = [&](size_t bytes) { size_t o = off; off += (bytes + 255) & ~(size_t)255; return (char*)d_ws + o; };
    // zero-group (one memset): cnt, bcur, stats0, stats1
    int*    cnt      = (int*)carve((size_t)N * 4);
    int*    bcur     = (int*)carve((size_t)NB * 4);
    float*  stats0   = (float*)carve(256 * 4);
    float*  stats1   = (float*)carve(256 * 4);
    size_t zero_span = (size_t)((char*)stats1 + 256 * 4 - (char*)cnt);
    int*    rowstart = (int*)carve((size_t)(N + 1) * 4);
    int*    csr      = (int*)carve((size_t)E * 4);
    int2*   tmp      = (int2*)carve((size_t)E * 8);
    float*  dinv     = (float*)carve((size_t)N * 4);
    int*    bsum     = (int*)carve(64 * 4);
    __half* W0t      = (__half*)carve(128 * 128 * 2);
    __half* W1t      = (__half*)carve(128 * 128 * 2);
    __half* W2t      = (__half*)carve(48 * 128 * 2);
    __half* HgH      = (__half*)carve((size_t)N * 128 * 2);
    __half* HaH      = (__half*)carve((size_t)N * 128 * 2);
    float*  Hg32     = (float*)carve((size_t)N * 40 * 4);

    hipMemsetAsync(cnt, 0, zero_span, stream);

    int SB = (N + 4095) / 4096;

    k_wt_all<<<(32768 + 48 * 128 + 255) / 256, 256, 0, stream>>>(W0, W1, W2, W0t, W1t, W2t, DOUT);
    k_count<<<(E + 255) / 256, 256, 0, stream>>>(dstp, cnt, E);
    k_scan_sum<<<SB, 256, 0, stream>>>(cnt, bsum, N);
    k_scan_apply<<<SB, 256, 0, stream>>>(cnt, bsum, rowstart, dinv, N, SB);
    k_bin<<<(E + 255) / 256, 256, 0, stream>>>(srcp, dstp, rowstart, bcur, tmp, E);
    k_scatter_local<<<NB, 256, 0, stream>>>(tmp, rowstart, csr, N);

    int gemm_blocks = (N + 63) / 64;
    int aggH_blocks = (N + 7) / 8;
    int aggO_blocks = (N + 15) / 16;

    // layer 1 (fp32 input, no BN)
    k_gemm_mfma<8, float, __half><<<gemm_blocks, 256, 0, stream>>>(x, W0t, nullptr, nullptr, nullptr, invN, dinv, HgH, N, 128);
    k_aggregate_h<<<aggH_blocks, 256, 0, stream>>>(HgH, csr, rowstart, dinv, b0, HaH, N);
    k_bn_stats_h<<<512, 256, 0, stream>>>(HaH, stats0, N);

    // layer 2 (BN0+ReLU fused into A-fragment, from raw sums)
    k_gemm_mfma<8, __half, __half><<<gemm_blocks, 256, 0, stream>>>(HaH, W1t, stats0, g0, bt0, invN, dinv, HgH, N, 128);
    k_aggregate_h<<<aggH_blocks, 256, 0, stream>>>(HgH, csr, rowstart, dinv, b1, HaH, N);
    k_bn_stats_h<<<512, 256, 0, stream>>>(HaH, stats1, N);

    // layer 3 (BN1+ReLU fused; fp32 out; aggregate fused with log_softmax)
    k_gemm_mfma<3, __half, float><<<gemm_blocks, 256, 0, stream>>>(HaH, W2t, stats1, g1, bt1, invN, dinv, Hg32, N, DOUT);
    k_aggregate_lsm<<<aggO_blocks, 256, 0, stream>>>(Hg32, csr, rowstart, dinv, b2, out, N, DOUT);
}

// Round 9
// 398.741 us; speedup vs baseline: 1.0004x; 1.0004x over previous
//
#include <hip/hip_runtime.h>
#include <hip/hip_fp16.h>
#include <cstdint>

typedef _Float16 f16x8 __attribute__((ext_vector_type(8)));
typedef float f32x4 __attribute__((ext_vector_type(4)));

// ---------------- graph preprocessing ----------------

__global__ __launch_bounds__(256) void k_count(const int* __restrict__ dst, int* __restrict__ cnt, int E) {
    int e = blockIdx.x * 256 + threadIdx.x;
    if (e < E) atomicAdd(&cnt[dst[e]], 1);
}

// per-4096-chunk sums of cnt
__global__ __launch_bounds__(256) void k_scan_sum(const int* __restrict__ cnt, int* __restrict__ bsum, int N) {
    int base = blockIdx.x * 4096 + threadIdx.x * 16;
    int s = 0;
    if (base + 16 <= N) {
        const int4* p = (const int4*)(cnt + base);
        int4 a = p[0], b = p[1], c = p[2], d = p[3];
        s = a.x + a.y + a.z + a.w + b.x + b.y + b.z + b.w
          + c.x + c.y + c.z + c.w + d.x + d.y + d.z + d.w;
    } else {
        for (int i = base; i < N; i++) s += cnt[i];
    }
    __shared__ int ws[4];
#pragma unroll
    for (int off = 32; off; off >>= 1) s += __shfl_down(s, off, 64);
    if ((threadIdx.x & 63) == 0) ws[threadIdx.x >> 6] = s;
    __syncthreads();
    if (threadIdx.x == 0) bsum[blockIdx.x] = ws[0] + ws[1] + ws[2] + ws[3];
}

// exclusive scan apply + rowstart[N] + dinv, fused
__global__ __launch_bounds__(256) void k_scan_apply(const int* __restrict__ cnt, const int* __restrict__ bsum,
                                                    int* __restrict__ rowstart, float* __restrict__ dinv,
                                                    int N, int SB) {
    __shared__ int boff_s;
    __shared__ int ls[256];
    int t = threadIdx.x;
    if (t == 0) {
        int run = 0;
        for (int i = 0; i < (int)blockIdx.x; i++) run += bsum[i];
        boff_s = run;
        if ((int)blockIdx.x == SB - 1) {
            int tot = run;
            for (int i = blockIdx.x; i < SB; i++) tot += bsum[i];
            rowstart[N] = tot;
        }
    }
    int base = blockIdx.x * 4096 + t * 16;
    int v[16], e[16];
    int s = 0;
    bool full = (base + 16 <= N);
    if (full) {
        const int4* p = (const int4*)(cnt + base);
        int4 q0 = p[0], q1 = p[1], q2 = p[2], q3 = p[3];
        int tmp[16] = {q0.x, q0.y, q0.z, q0.w, q1.x, q1.y, q1.z, q1.w,
                       q2.x, q2.y, q2.z, q2.w, q3.x, q3.y, q3.z, q3.w};
#pragma unroll
        for (int j = 0; j < 16; j++) { e[j] = tmp[j]; v[j] = s; s += e[j]; }
    } else {
#pragma unroll
        for (int j = 0; j < 16; j++) { int i = base + j; e[j] = (i < N) ? cnt[i] : 0; v[j] = s; s += e[j]; }
    }
    ls[t] = s;
    __syncthreads();
    for (int off = 1; off < 256; off <<= 1) {
        int o = (t >= off) ? ls[t - off] : 0;
        __syncthreads();
        ls[t] += o;
        __syncthreads();
    }
    int excl = ls[t] - s + boff_s;
    if (full) {
        int w[16];
        float dv[16];
#pragma unroll
        for (int j = 0; j < 16; j++) { w[j] = v[j] + excl; dv[j] = rsqrtf((float)(e[j] + 1)); }
        int4* p = (int4*)(rowstart + base);
        p[0] = make_int4(w[0], w[1], w[2], w[3]);
        p[1] = make_int4(w[4], w[5], w[6], w[7]);
        p[2] = make_int4(w[8], w[9], w[10], w[11]);
        p[3] = make_int4(w[12], w[13], w[14], w[15]);
        float4* q = (float4*)(dinv + base);
        q[0] = make_float4(dv[0], dv[1], dv[2], dv[3]);
        q[1] = make_float4(dv[4], dv[5], dv[6], dv[7]);
        q[2] = make_float4(dv[8], dv[9], dv[10], dv[11]);
        q[3] = make_float4(dv[12], dv[13], dv[14], dv[15]);
    } else {
        for (int j = 0; j < 16; j++) {
            int i = base + j;
            if (i < N) { rowstart[i] = v[j] + excl; dinv[i] = rsqrtf((float)(e[j] + 1)); }
        }
    }
}

// ---- two-phase binned scatter: bucket = 32-node range, CSR-contiguous ----

// phase 1: edge -> tmp[bucket region], payload (dst, src)
__global__ __launch_bounds__(256) void k_bin(const int* __restrict__ src, const int* __restrict__ dst,
                                             const int* __restrict__ rowstart, int* __restrict__ bcur,
                                             int2* __restrict__ tmp, int E) {
    int e = blockIdx.x * 256 + threadIdx.x;
    if (e >= E) return;
    int d = dst[e];
    int b = d >> 5;
    int pos = rowstart[b << 5] + atomicAdd(&bcur[b], 1);
    tmp[pos] = make_int2(d, src[e]);
}

// phase 2: one block per bucket; LDS rowstart window + LDS cursors; local csr writes
__global__ __launch_bounds__(256) void k_scatter_local(const int2* __restrict__ tmp, const int* __restrict__ rowstart,
                                                       int* __restrict__ csr, int N) {
    __shared__ int lcur[32];
    __shared__ int rw[33];
    int lo = blockIdx.x << 5;
    int nn = min(32, N - lo);
    int t = threadIdx.x;
    if (t < 32) lcur[t] = 0;
    if (t < nn + 1) rw[t] = rowstart[lo + t];
    __syncthreads();
    int e0 = rw[0], e1 = rw[nn];
    for (int i = e0 + t; i < e1; i += 256) {
        int2 p = tmp[i];
        int pos = rw[p.x - lo] + atomicAdd(&lcur[p.x - lo], 1);
        csr[pos] = p.y;
    }
}

// ---------------- weight transposes (all 3 in one launch) ----------------

__global__ __launch_bounds__(256) void k_wt_all(const float* __restrict__ W0, const float* __restrict__ W1,
                                                const float* __restrict__ W2,
                                                __half* __restrict__ W0t, __half* __restrict__ W1t,
                                                __half* __restrict__ W2t, int DOUT) {
    int idx = blockIdx.x * 256 + threadIdx.x;
    if (idx < 16384) {
        int c = idx >> 7, k = idx & 127;
        W0t[idx] = __float2half(W0[k * 128 + c]);
    } else if (idx < 32768) {
        int i = idx - 16384;
        int c = i >> 7, k = i & 127;
        W1t[i] = __float2half(W1[k * 128 + c]);
    } else if (idx < 32768 + 48 * 128) {
        int i = idx - 32768;
        int c = i >> 7, k = i & 127;
        W2t[i] = (c < DOUT) ? __float2half(W2[k * DOUT + c]) : __half(0);
    }
}

// ---------------- dtype helpers ----------------

__device__ inline void store1f(float* p, float v) { *p = v; }
__device__ inline void store1f(__half* p, float v) { *p = __float2half(v); }

__device__ inline f16x8 load_a8(const __half* p) { return *(const f16x8*)p; }
__device__ inline f16x8 load_a8(const float* p) {
    float4 a = *(const float4*)p;
    float4 b = *(const float4*)(p + 4);
    f16x8 r;
    r[0] = (_Float16)a.x; r[1] = (_Float16)a.y; r[2] = (_Float16)a.z; r[3] = (_Float16)a.w;
    r[4] = (_Float16)b.x; r[5] = (_Float16)b.y; r[6] = (_Float16)b.z; r[7] = (_Float16)b.w;
    return r;
}

// ---------------- MFMA GEMM ----------------

template<int CT, typename InT, typename OutT>
__global__ __launch_bounds__(256) void k_gemm_mfma(const InT* __restrict__ A,
                                                   const __half* __restrict__ Wt,
                                                   const float* __restrict__ sums,
                                                   const float* __restrict__ g,
                                                   const float* __restrict__ bt,
                                                   float invN,
                                                   const float* __restrict__ dscale,
                                                   OutT* __restrict__ C, int M, int NC) {
    int lane = threadIdx.x & 63;
    int r0 = blockIdx.x * 64 + (threadIdx.x >> 6) * 16;
    if (r0 >= M) return;
    int lrow = lane & 15;
    int lk = (lane >> 4) << 3;

    f16x8 b[CT][4];
#pragma unroll
    for (int c = 0; c < CT; c++)
#pragma unroll
        for (int kt = 0; kt < 4; kt++)
            b[c][kt] = *(const f16x8*)(Wt + (size_t)(c * 16 + lrow) * 128 + kt * 32 + lk);

    f32x4 acc[CT];
#pragma unroll
    for (int c = 0; c < CT; c++) acc[c] = f32x4{0.f, 0.f, 0.f, 0.f};

    int row = r0 + lrow;
    bool rv = (row < M);
    const InT* Arow = A + (size_t)(rv ? row : 0) * 128 + lk;

#pragma unroll
    for (int kt = 0; kt < 4; kt++) {
        f16x8 a = load_a8(Arow + kt * 32);
        if (!rv) a = f16x8{};
        if (sums) {
            int ch = kt * 32 + lk;
            float4 s1a = *(const float4*)(sums + ch);
            float4 s1b = *(const float4*)(sums + ch + 4);
            float4 s2a = *(const float4*)(sums + 128 + ch);
            float4 s2b = *(const float4*)(sums + 128 + ch + 4);
            float4 ga  = *(const float4*)(g + ch);
            float4 gb  = *(const float4*)(g + ch + 4);
            float4 ba  = *(const float4*)(bt + ch);
            float4 bb  = *(const float4*)(bt + ch + 4);
            float s1v[8] = {s1a.x, s1a.y, s1a.z, s1a.w, s1b.x, s1b.y, s1b.z, s1b.w};
            float s2v[8] = {s2a.x, s2a.y, s2a.z, s2a.w, s2b.x, s2b.y, s2b.z, s2b.w};
            float gv[8]  = {ga.x, ga.y, ga.z, ga.w, gb.x, gb.y, gb.z, gb.w};
            float btv[8] = {ba.x, ba.y, ba.z, ba.w, bb.x, bb.y, bb.z, bb.w};
#pragma unroll
            for (int j = 0; j < 8; j++) {
                float mu  = s1v[j] * invN;
                float var = s2v[j] * invN - mu * mu;
                float w   = rsqrtf(var + 1e-5f) * gv[j];
                float sh  = btv[j] - mu * w;
                a[j] = (_Float16)fmaxf(fmaf((float)a[j], w, sh), 0.f);
            }
        }
#pragma unroll
        for (int c = 0; c < CT; c++)
            acc[c] = __builtin_amdgcn_mfma_f32_16x16x32_f16(a, b[c][kt], acc[c], 0, 0, 0);
    }

    int rbase = r0 + ((lane >> 4) << 2);
    float4 ds4 = *(const float4*)(dscale + rbase);
    float dsv[4] = {ds4.x, ds4.y, ds4.z, ds4.w};
#pragma unroll
    for (int c = 0; c < CT; c++) {
        int col = c * 16 + lrow;
        if (col >= NC) continue;
#pragma unroll
        for (int reg = 0; reg < 4; reg++) {
            int r = rbase + reg;
            if (r < M) store1f(C + (size_t)r * NC + col, acc[c][reg] * dsv[reg]);
        }
    }
}

// ---------------- aggregation, fp16 gather (D=128), fp16 out ----------------

__device__ inline void acc_h4(float2 raw, float& ax, float& ay, float& az, float& aw) {
    union { float f; __half2 h; } u0, u1;
    u0.f = raw.x; u1.f = raw.y;
    float2 f01 = __half22float2(u0.h);
    float2 f23 = __half22float2(u1.h);
    ax += f01.x; ay += f01.y; az += f23.x; aw += f23.y;
}

__global__ __launch_bounds__(256) void k_aggregate_h(const __half* __restrict__ Hs, const int* __restrict__ csr,
                                                     const int* __restrict__ rowstart, const float* __restrict__ dinv,
                                                     const float* __restrict__ bias, __half* __restrict__ out, int N) {
    int node = blockIdx.x * 8 + (threadIdx.x >> 5);
    int lane = threadIdx.x & 31;
    int c = lane << 2;
    if (node >= N) return;

    int s0 = rowstart[node], s1 = rowstart[node + 1];
    float ax = 0.f, ay = 0.f, az = 0.f, aw = 0.f;

    int j = s0;
    for (; j + 8 <= s1; j += 8) {
        int i0 = csr[j + 0], i1 = csr[j + 1], i2 = csr[j + 2], i3 = csr[j + 3];
        int i4 = csr[j + 4], i5 = csr[j + 5], i6 = csr[j + 6], i7 = csr[j + 7];
        float2 r0 = *(const float2*)(Hs + (size_t)i0 * 128 + c);
        float2 r1 = *(const float2*)(Hs + (size_t)i1 * 128 + c);
        float2 r2 = *(const float2*)(Hs + (size_t)i2 * 128 + c);
        float2 r3 = *(const float2*)(Hs + (size_t)i3 * 128 + c);
        float2 r4 = *(const float2*)(Hs + (size_t)i4 * 128 + c);
        float2 r5 = *(const float2*)(Hs + (size_t)i5 * 128 + c);
        float2 r6 = *(const float2*)(Hs + (size_t)i6 * 128 + c);
        float2 r7 = *(const float2*)(Hs + (size_t)i7 * 128 + c);
        acc_h4(r0, ax, ay, az, aw); acc_h4(r1, ax, ay, az, aw);
        acc_h4(r2, ax, ay, az, aw); acc_h4(r3, ax, ay, az, aw);
        acc_h4(r4, ax, ay, az, aw); acc_h4(r5, ax, ay, az, aw);
        acc_h4(r6, ax, ay, az, aw); acc_h4(r7, ax, ay, az, aw);
    }
    for (; j < s1; j++) {
        int s = csr[j];
        float2 r = *(const float2*)(Hs + (size_t)s * 128 + c);
        acc_h4(r, ax, ay, az, aw);
    }

    float2 rs = *(const float2*)(Hs + (size_t)node * 128 + c);
    acc_h4(rs, ax, ay, az, aw);

    float dn = dinv[node];
    float4 b4 = *(const float4*)(bias + c);
    union { __half2 h[2]; float2 f; } u;
    u.h[0] = __floats2half2_rn(ax * dn + b4.x, ay * dn + b4.y);
    u.h[1] = __floats2half2_rn(az * dn + b4.z, aw * dn + b4.w);
    *(float2*)(out + (size_t)node * 128 + c) = u.f;
}

// ---------------- aggregation + log_softmax, fp32 (layer 3, D<=64) ----------------

__global__ __launch_bounds__(256) void k_aggregate_lsm(const float* __restrict__ Hs, const int* __restrict__ csr,
                                                       const int* __restrict__ rowstart, const float* __restrict__ dinv,
                                                       const float* __restrict__ bias, float* __restrict__ out,
                                                       int N, int D) {
    int node = blockIdx.x * 16 + (threadIdx.x >> 4);
    int lane = threadIdx.x & 15;
    int c = lane << 2;
    if (node >= N) return;
    bool act = c < D;

    int s0 = rowstart[node], s1 = rowstart[node + 1];
    float ax = 0.f, ay = 0.f, az = 0.f, aw = 0.f;

    int j = s0;
    for (; j + 8 <= s1; j += 8) {
        int i0 = csr[j + 0], i1 = csr[j + 1], i2 = csr[j + 2], i3 = csr[j + 3];
        int i4 = csr[j + 4], i5 = csr[j + 5], i6 = csr[j + 6], i7 = csr[j + 7];
        if (act) {
            float4 v0 = *(const float4*)(Hs + (size_t)i0 * D + c);
            float4 v1 = *(const float4*)(Hs + (size_t)i1 * D + c);
            float4 v2 = *(const float4*)(Hs + (size_t)i2 * D + c);
            float4 v3 = *(const float4*)(Hs + (size_t)i3 * D + c);
            float4 v4 = *(const float4*)(Hs + (size_t)i4 * D + c);
            float4 v5 = *(const float4*)(Hs + (size_t)i5 * D + c);
            float4 v6 = *(const float4*)(Hs + (size_t)i6 * D + c);
            float4 v7 = *(const float4*)(Hs + (size_t)i7 * D + c);
            ax += v0.x; ay += v0.y; az += v0.z; aw += v0.w;
            ax += v1.x; ay += v1.y; az += v1.z; aw += v1.w;
            ax += v2.x; ay += v2.y; az += v2.z; aw += v2.w;
            ax += v3.x; ay += v3.y; az += v3.z; aw += v3.w;
            ax += v4.x; ay += v4.y; az += v4.z; aw += v4.w;
            ax += v5.x; ay += v5.y; az += v5.z; aw += v5.w;
            ax += v6.x; ay += v6.y; az += v6.z; aw += v6.w;
            ax += v7.x; ay += v7.y; az += v7.z; aw += v7.w;
        }
    }
    for (; j < s1; j++) {
        int s = csr[j];
        if (act) {
            float4 v = *(const float4*)(Hs + (size_t)s * D + c);
            ax += v.x; ay += v.y; az += v.z; aw += v.w;
        }
    }

    float4 r = make_float4(0.f, 0.f, 0.f, 0.f);
    if (act) {
        float4 self = *(const float4*)(Hs + (size_t)node * D + c);
        float dn = dinv[node];
        float4 b4 = *(const float4*)(bias + c);
        r.x = (ax + self.x) * dn + b4.x;
        r.y = (ay + self.y) * dn + b4.y;
        r.z = (az + self.z) * dn + b4.z;
        r.w = (aw + self.w) * dn + b4.w;
    }

    float m = act ? fmaxf(fmaxf(r.x, r.y), fmaxf(r.z, r.w)) : -1e30f;
#pragma unroll
    for (int off = 8; off; off >>= 1) m = fmaxf(m, __shfl_xor(m, off, 16));
    float es = act ? (expf(r.x - m) + expf(r.y - m) + expf(r.z - m) + expf(r.w - m)) : 0.f;
#pragma unroll
    for (int off = 8; off; off >>= 1) es += __shfl_xor(es, off, 16);
    float ls = logf(es);
    if (act) {
        float4 o = make_float4(r.x - m - ls, r.y - m - ls, r.z - m - ls, r.w - m - ls);
        *(float4*)(out + (size_t)node * D + c) = o;
    }
}

// ---------------- BatchNorm stats (fp16 input) ----------------

__global__ __launch_bounds__(256) void k_bn_stats_h(const __half* __restrict__ H, float* __restrict__ sums, int N) {
    __shared__ float ls[256], ls2[256];
    int c = threadIdx.x & 127;
    int half = threadIdx.x >> 7;
    float s = 0.f, s2 = 0.f;
    for (int r = blockIdx.x * 2 + half; r < N; r += gridDim.x * 2) {
        float v = __half2float(H[(size_t)r * 128 + c]);
        s += v; s2 += v * v;
    }
    ls[threadIdx.x] = s; ls2[threadIdx.x] = s2;
    __syncthreads();
    if (threadIdx.x < 128) {
        atomicAdd(&sums[c], ls[threadIdx.x] + ls[threadIdx.x + 128]);
        atomicAdd(&sums[128 + c], ls2[threadIdx.x] + ls2[threadIdx.x + 128]);
    }
}

// ---------------- launch ----------------

extern "C" void kernel_launch(void* const* d_in, const int* in_sizes, int n_in,
                              void* d_out, int out_size, void* d_ws, size_t ws_size,
                              hipStream_t stream) {
    const float* x   = (const float*)d_in[0];
    const int*   ei  = (const int*)d_in[1];
    const float* W0  = (const float*)d_in[2];
    const float* b0  = (const float*)d_in[3];
    const float* W1  = (const float*)d_in[4];
    const float* b1  = (const float*)d_in[5];
    const float* W2  = (const float*)d_in[6];
    const float* b2  = (const float*)d_in[7];
    const float* g0  = (const float*)d_in[8];
    const float* bt0 = (const float*)d_in[9];
    const float* g1  = (const float*)d_in[10];
    const float* bt1 = (const float*)d_in[11];
    float* out = (float*)d_out;

    int N    = in_sizes[0] / 128;
    int E    = in_sizes[1] / 2;
    int DOUT = in_sizes[7];          // 40
    float invN = 1.0f / (float)N;

    const int* srcp = ei;
    const int* dstp = ei + E;

    int NB = (N + 31) / 32;          // scatter buckets (32 nodes each)

    size_t off = 0;
    auto carve = [&](size_t bytes) { size_t o = off; off += (bytes + 255) & ~(size_t)255; return (char*)d_ws + o; };
    // zero-group (one memset): cnt, bcur, stats0, stats1
    int*    cnt      = (int*)carve((size_t)N * 4);
    int*    bcur     = (int*)carve((size_t)NB * 4);
    float*  stats0   = (float*)carve(256 * 4);
    float*  stats1   = (float*)carve(256 * 4);
    size_t zero_span = (size_t)((char*)stats1 + 256 * 4 - (char*)cnt);
    int*    rowstart = (int*)carve((size_t)(N + 1) * 4);
    int*    csr      = (int*)carve((size_t)E * 4);
    int2*   tmp      = (int2*)carve((size_t)E * 8);
    float*  dinv     = (float*)carve((size_t)N * 4);
    int*    bsum     = (int*)carve(64 * 4);
    __half* W0t      = (__half*)carve(128 * 128 * 2);
    __half* W1t      = (__half*)carve(128 * 128 * 2);
    __half* W2t      = (__half*)carve(48 * 128 * 2);
    __half* HgH      = (__half*)carve((size_t)N * 128 * 2);
    __half* HaH      = (__half*)carve((size_t)N * 128 * 2);
    float*  Hg32     = (float*)carve((size_t)N * 40 * 4);

    hipMemsetAsync(cnt, 0, zero_span, stream);

    int SB = (N + 4095) / 4096;

    k_wt_all<<<(32768 + 48 * 128 + 255) / 256, 256, 0, stream>>>(W0, W1, W2, W0t, W1t, W2t, DOUT);
    k_count<<<(E + 255) / 256, 256, 0, stream>>>(dstp, cnt, E);
    k_scan_sum<<<SB, 256, 0, stream>>>(cnt, bsum, N);
    k_scan_apply<<<SB, 256, 0, stream>>>(cnt, bsum, rowstart, dinv, N, SB);
    k_bin<<<(E + 255) / 256, 256, 0, stream>>>(srcp, dstp, rowstart, bcur, tmp, E);
    k_scatter_local<<<NB, 256, 0, stream>>>(tmp, rowstart, csr, N);

    int gemm_blocks = (N + 63) / 64;
    int aggH_blocks = (N + 7) / 8;
    int aggO_blocks = (N + 15) / 16;

    // layer 1 (fp32 input, no BN)
    k_gemm_mfma<8, float, __half><<<gemm_blocks, 256, 0, stream>>>(x, W0t, nullptr, nullptr, nullptr, invN, dinv, HgH, N, 128);
    k_aggregate_h<<<aggH_blocks, 256, 0, stream>>>(HgH, csr, rowstart, dinv, b0, HaH, N);
    k_bn_stats_h<<<512, 256, 0, stream>>>(HaH, stats0, N);

    // layer 2 (BN0+ReLU fused into A-fragment, from raw sums)
    k_gemm_mfma<8, __half, __half><<<gemm_blocks, 256, 0, stream>>>(HaH, W1t, stats0, g0, bt0, invN, dinv, HgH, N, 128);
    k_aggregate_h<<<aggH_blocks, 256, 0, stream>>>(HgH, csr, rowstart, dinv, b1, HaH, N);
    k_bn_stats_h<<<512, 256, 0, stream>>>(HaH, stats1, N);

    // layer 3 (BN1+ReLU fused; fp32 out; aggregate fused with log_softmax)
    k_gemm_mfma<3, __half, float><<<gemm_blocks, 256, 0, stream>>>(HaH, W2t, stats1, g1, bt1, invN, dinv, Hg32, N, DOUT);
    k_aggregate_lsm<<<aggO_blocks, 256, 0, stream>>>(Hg32, csr, rowstart, dinv, b2, out, N, DOUT);
}

// Round 10
// 321.440 us; speedup vs baseline: 1.2410x; 1.2405x over previous
//
#include <hip/hip_runtime.h>
#include <hip/hip_fp16.h>
#include <cstdint>

typedef _Float16 f16x8 __attribute__((ext_vector_type(8)));
typedef float f32x4 __attribute__((ext_vector_type(4)));
typedef float f2v __attribute__((ext_vector_type(2)));

// ---------------- graph preprocessing ----------------

// per-4096-chunk sums of cnt
__global__ __launch_bounds__(256) void k_scan_sum(const int* __restrict__ cnt, int* __restrict__ bsum, int N) {
    int base = blockIdx.x * 4096 + threadIdx.x * 16;
    int s = 0;
    if (base + 16 <= N) {
        const int4* p = (const int4*)(cnt + base);
        int4 a = p[0], b = p[1], c = p[2], d = p[3];
        s = a.x + a.y + a.z + a.w + b.x + b.y + b.z + b.w
          + c.x + c.y + c.z + c.w + d.x + d.y + d.z + d.w;
    } else {
        for (int i = base; i < N; i++) s += cnt[i];
    }
    __shared__ int ws[4];
#pragma unroll
    for (int off = 32; off; off >>= 1) s += __shfl_down(s, off, 64);
    if ((threadIdx.x & 63) == 0) ws[threadIdx.x >> 6] = s;
    __syncthreads();
    if (threadIdx.x == 0) bsum[blockIdx.x] = ws[0] + ws[1] + ws[2] + ws[3];
}

// exclusive scan apply + rowstart[N] + dinv, fused
__global__ __launch_bounds__(256) void k_scan_apply(const int* __restrict__ cnt, const int* __restrict__ bsum,
                                                    int* __restrict__ rowstart, float* __restrict__ dinv,
                                                    int N, int SB) {
    __shared__ int boff_s;
    __shared__ int ls[256];
    int t = threadIdx.x;
    if (t == 0) {
        int run = 0;
        for (int i = 0; i < (int)blockIdx.x; i++) run += bsum[i];
        boff_s = run;
        if ((int)blockIdx.x == SB - 1) {
            int tot = run;
            for (int i = blockIdx.x; i < SB; i++) tot += bsum[i];
            rowstart[N] = tot;
        }
    }
    int base = blockIdx.x * 4096 + t * 16;
    int v[16], e[16];
    int s = 0;
    bool full = (base + 16 <= N);
    if (full) {
        const int4* p = (const int4*)(cnt + base);
        int4 q0 = p[0], q1 = p[1], q2 = p[2], q3 = p[3];
        int tmp[16] = {q0.x, q0.y, q0.z, q0.w, q1.x, q1.y, q1.z, q1.w,
                       q2.x, q2.y, q2.z, q2.w, q3.x, q3.y, q3.z, q3.w};
#pragma unroll
        for (int j = 0; j < 16; j++) { e[j] = tmp[j]; v[j] = s; s += e[j]; }
    } else {
#pragma unroll
        for (int j = 0; j < 16; j++) { int i = base + j; e[j] = (i < N) ? cnt[i] : 0; v[j] = s; s += e[j]; }
    }
    ls[t] = s;
    __syncthreads();
    for (int off = 1; off < 256; off <<= 1) {
        int o = (t >= off) ? ls[t - off] : 0;
        __syncthreads();
        ls[t] += o;
        __syncthreads();
    }
    int excl = ls[t] - s + boff_s;
    if (full) {
        int w[16];
        float dv[16];
#pragma unroll
        for (int j = 0; j < 16; j++) { w[j] = v[j] + excl; dv[j] = rsqrtf((float)(e[j] + 1)); }
        int4* p = (int4*)(rowstart + base);
        p[0] = make_int4(w[0], w[1], w[2], w[3]);
        p[1] = make_int4(w[4], w[5], w[6], w[7]);
        p[2] = make_int4(w[8], w[9], w[10], w[11]);
        p[3] = make_int4(w[12], w[13], w[14], w[15]);
        float4* q = (float4*)(dinv + base);
        q[0] = make_float4(dv[0], dv[1], dv[2], dv[3]);
        q[1] = make_float4(dv[4], dv[5], dv[6], dv[7]);
        q[2] = make_float4(dv[8], dv[9], dv[10], dv[11]);
        q[3] = make_float4(dv[12], dv[13], dv[14], dv[15]);
    } else {
        for (int j = 0; j < 16; j++) {
            int i = base + j;
            if (i < N) { rowstart[i] = v[j] + excl; dinv[i] = rsqrtf((float)(e[j] + 1)); }
        }
    }
}

// ---------------- fused: weight transpose (blocks [0,WTB)) + degree count (rest) ----------------
// W[k][c] fp32 -> Wt[c][k] fp16, W2 zero-padded to 48 cols. count: NT edge reads.

__global__ __launch_bounds__(256) void k_wt_count(const float* __restrict__ W0, const float* __restrict__ W1,
                                                  const float* __restrict__ W2,
                                                  __half* __restrict__ W0t, __half* __restrict__ W1t,
                                                  __half* __restrict__ W2t, int DOUT,
                                                  const int* __restrict__ dst, int* __restrict__ cnt, int E,
                                                  int WTB) {
    if ((int)blockIdx.x < WTB) {
        int idx = blockIdx.x * 256 + threadIdx.x;
        if (idx < 16384) {
            int c = idx >> 7, k = idx & 127;
            W0t[idx] = __float2half(W0[k * 128 + c]);
        } else if (idx < 32768) {
            int i = idx - 16384;
            int c = i >> 7, k = i & 127;
            W1t[i] = __float2half(W1[k * 128 + c]);
        } else if (idx < 32768 + 48 * 128) {
            int i = idx - 32768;
            int c = i >> 7, k = i & 127;
            W2t[i] = (c < DOUT) ? __float2half(W2[k * DOUT + c]) : __half(0);
        }
    } else {
        int e = (blockIdx.x - WTB) * 256 + threadIdx.x;
        if (e < E) {
            int d = __builtin_nontemporal_load(dst + e);
            atomicAdd(&cnt[d], 1);
        }
    }
}

// ---------------- dtype helpers ----------------

__device__ inline void store1f(float* p, float v) { *p = v; }
__device__ inline void store1f(__half* p, float v) { *p = __float2half(v); }

__device__ inline f16x8 load_a8(const __half* p) { return *(const f16x8*)p; }
__device__ inline f16x8 load_a8(const float* p) {
    float4 a = *(const float4*)p;
    float4 b = *(const float4*)(p + 4);
    f16x8 r;
    r[0] = (_Float16)a.x; r[1] = (_Float16)a.y; r[2] = (_Float16)a.z; r[3] = (_Float16)a.w;
    r[4] = (_Float16)b.x; r[5] = (_Float16)b.y; r[6] = (_Float16)b.z; r[7] = (_Float16)b.w;
    return r;
}

// ---------------- MFMA GEMM body ----------------

template<int CT, typename InT, typename OutT>
__device__ __forceinline__ void gemm_body(int bid, const InT* __restrict__ A,
                                          const __half* __restrict__ Wt,
                                          const float* __restrict__ sums,
                                          const float* __restrict__ g,
                                          const float* __restrict__ bt,
                                          float invN,
                                          const float* __restrict__ dscale,
                                          OutT* __restrict__ C, int M, int NC) {
    int lane = threadIdx.x & 63;
    int r0 = bid * 64 + (threadIdx.x >> 6) * 16;
    if (r0 >= M) return;
    int lrow = lane & 15;
    int lk = (lane >> 4) << 3;

    f16x8 b[CT][4];
#pragma unroll
    for (int c = 0; c < CT; c++)
#pragma unroll
        for (int kt = 0; kt < 4; kt++)
            b[c][kt] = *(const f16x8*)(Wt + (size_t)(c * 16 + lrow) * 128 + kt * 32 + lk);

    f32x4 acc[CT];
#pragma unroll
    for (int c = 0; c < CT; c++) acc[c] = f32x4{0.f, 0.f, 0.f, 0.f};

    int row = r0 + lrow;
    bool rv = (row < M);
    const InT* Arow = A + (size_t)(rv ? row : 0) * 128 + lk;

#pragma unroll
    for (int kt = 0; kt < 4; kt++) {
        f16x8 a = load_a8(Arow + kt * 32);
        if (!rv) a = f16x8{};
        if (sums) {
            int ch = kt * 32 + lk;
            float4 s1a = *(const float4*)(sums + ch);
            float4 s1b = *(const float4*)(sums + ch + 4);
            float4 s2a = *(const float4*)(sums + 128 + ch);
            float4 s2b = *(const float4*)(sums + 128 + ch + 4);
            float4 ga  = *(const float4*)(g + ch);
            float4 gb  = *(const float4*)(g + ch + 4);
            float4 ba  = *(const float4*)(bt + ch);
            float4 bb  = *(const float4*)(bt + ch + 4);
            float s1v[8] = {s1a.x, s1a.y, s1a.z, s1a.w, s1b.x, s1b.y, s1b.z, s1b.w};
            float s2v[8] = {s2a.x, s2a.y, s2a.z, s2a.w, s2b.x, s2b.y, s2b.z, s2b.w};
            float gv[8]  = {ga.x, ga.y, ga.z, ga.w, gb.x, gb.y, gb.z, gb.w};
            float btv[8] = {ba.x, ba.y, ba.z, ba.w, bb.x, bb.y, bb.z, bb.w};
#pragma unroll
            for (int j = 0; j < 8; j++) {
                float mu  = s1v[j] * invN;
                float var = s2v[j] * invN - mu * mu;
                float w   = rsqrtf(var + 1e-5f) * gv[j];
                float sh  = btv[j] - mu * w;
                a[j] = (_Float16)fmaxf(fmaf((float)a[j], w, sh), 0.f);
            }
        }
#pragma unroll
        for (int c = 0; c < CT; c++)
            acc[c] = __builtin_amdgcn_mfma_f32_16x16x32_f16(a, b[c][kt], acc[c], 0, 0, 0);
    }

    int rbase = r0 + ((lane >> 4) << 2);
    float4 ds4 = *(const float4*)(dscale + rbase);
    float dsv[4] = {ds4.x, ds4.y, ds4.z, ds4.w};
#pragma unroll
    for (int c = 0; c < CT; c++) {
        int col = c * 16 + lrow;
        if (col >= NC) continue;
#pragma unroll
        for (int reg = 0; reg < 4; reg++) {
            int r = rbase + reg;
            if (r < M) store1f(C + (size_t)r * NC + col, acc[c][reg] * dsv[reg]);
        }
    }
}

template<int CT, typename InT, typename OutT>
__global__ __launch_bounds__(256) void k_gemm_mfma(const InT* __restrict__ A, const __half* __restrict__ Wt,
                                                   const float* __restrict__ sums, const float* __restrict__ g,
                                                   const float* __restrict__ bt, float invN,
                                                   const float* __restrict__ dscale,
                                                   OutT* __restrict__ C, int M, int NC) {
    gemm_body<CT, InT, OutT>(blockIdx.x, A, Wt, sums, g, bt, invN, dscale, C, M, NC);
}

// ---------------- fused: layer-1 GEMM (blocks [0,GB)) + CSR scatter (rest) ----------------
// independent work items co-scheduled: scatter is atomic/latency-bound (0.5% VALU),
// gemm is compute-bound; overlapping removes gemm1 from the critical path.

__global__ __launch_bounds__(256) void k_gemm1_scatter(const float* __restrict__ A, const __half* __restrict__ Wt,
                                                       const float* __restrict__ dscale, __half* __restrict__ C,
                                                       int M, int NC, int GB,
                                                       const int* __restrict__ src, const int* __restrict__ dst,
                                                       const int* __restrict__ rowstart, int* __restrict__ cursor,
                                                       int* __restrict__ csr, int E) {
    if ((int)blockIdx.x < GB) {
        gemm_body<8, float, __half>(blockIdx.x, A, Wt, nullptr, nullptr, nullptr, 0.f, dscale, C, M, NC);
    } else {
        int e = (blockIdx.x - GB) * 256 + threadIdx.x;
        if (e < E) {
            int d = __builtin_nontemporal_load(dst + e);
            int s = __builtin_nontemporal_load(src + e);
            int pos = rowstart[d] + atomicAdd(&cursor[d], 1);
            csr[pos] = s;
        }
    }
}

// ---------------- aggregation, fp16 gather (D=128), fp16 out ----------------

__device__ inline void acc_h4(f2v raw, float& ax, float& ay, float& az, float& aw) {
    union { float f; __half2 h; } u0, u1;
    u0.f = raw.x; u1.f = raw.y;
    float2 f01 = __half22float2(u0.h);
    float2 f23 = __half22float2(u1.h);
    ax += f01.x; ay += f01.y; az += f23.x; aw += f23.y;
}

__global__ __launch_bounds__(256) void k_aggregate_h(const __half* __restrict__ Hs, const int* __restrict__ csr,
                                                     const int* __restrict__ rowstart, const float* __restrict__ dinv,
                                                     const float* __restrict__ bias, __half* __restrict__ out, int N) {
    int node = blockIdx.x * 8 + (threadIdx.x >> 5);
    int lane = threadIdx.x & 31;
    int c = lane << 2;
    if (node >= N) return;

    int s0 = rowstart[node], s1 = rowstart[node + 1];
    float ax = 0.f, ay = 0.f, az = 0.f, aw = 0.f;

    int j = s0;
    for (; j + 8 <= s1; j += 8) {
        int i0 = __builtin_nontemporal_load(csr + j + 0);
        int i1 = __builtin_nontemporal_load(csr + j + 1);
        int i2 = __builtin_nontemporal_load(csr + j + 2);
        int i3 = __builtin_nontemporal_load(csr + j + 3);
        int i4 = __builtin_nontemporal_load(csr + j + 4);
        int i5 = __builtin_nontemporal_load(csr + j + 5);
        int i6 = __builtin_nontemporal_load(csr + j + 6);
        int i7 = __builtin_nontemporal_load(csr + j + 7);
        f2v r0 = *(const f2v*)(Hs + (size_t)i0 * 128 + c);
        f2v r1 = *(const f2v*)(Hs + (size_t)i1 * 128 + c);
        f2v r2 = *(const f2v*)(Hs + (size_t)i2 * 128 + c);
        f2v r3 = *(const f2v*)(Hs + (size_t)i3 * 128 + c);
        f2v r4 = *(const f2v*)(Hs + (size_t)i4 * 128 + c);
        f2v r5 = *(const f2v*)(Hs + (size_t)i5 * 128 + c);
        f2v r6 = *(const f2v*)(Hs + (size_t)i6 * 128 + c);
        f2v r7 = *(const f2v*)(Hs + (size_t)i7 * 128 + c);
        acc_h4(r0, ax, ay, az, aw); acc_h4(r1, ax, ay, az, aw);
        acc_h4(r2, ax, ay, az, aw); acc_h4(r3, ax, ay, az, aw);
        acc_h4(r4, ax, ay, az, aw); acc_h4(r5, ax, ay, az, aw);
        acc_h4(r6, ax, ay, az, aw); acc_h4(r7, ax, ay, az, aw);
    }
    for (; j < s1; j++) {
        int s = __builtin_nontemporal_load(csr + j);
        f2v r = *(const f2v*)(Hs + (size_t)s * 128 + c);
        acc_h4(r, ax, ay, az, aw);
    }

    f2v rs = *(const f2v*)(Hs + (size_t)node * 128 + c);
    acc_h4(rs, ax, ay, az, aw);

    float dn = dinv[node];
    float4 b4 = *(const float4*)(bias + c);
    union { __half2 h[2]; f2v f; } u;
    u.h[0] = __floats2half2_rn(ax * dn + b4.x, ay * dn + b4.y);
    u.h[1] = __floats2half2_rn(az * dn + b4.z, aw * dn + b4.w);
    __builtin_nontemporal_store(u.f, (f2v*)(out + (size_t)node * 128 + c));
}

// ---------------- aggregation + log_softmax, fp32 (layer 3, D<=64) ----------------

__global__ __launch_bounds__(256) void k_aggregate_lsm(const float* __restrict__ Hs, const int* __restrict__ csr,
                                                       const int* __restrict__ rowstart, const float* __restrict__ dinv,
                                                       const float* __restrict__ bias, float* __restrict__ out,
                                                       int N, int D) {
    int node = blockIdx.x * 16 + (threadIdx.x >> 4);
    int lane = threadIdx.x & 15;
    int c = lane << 2;
    if (node >= N) return;
    bool act = c < D;

    int s0 = rowstart[node], s1 = rowstart[node + 1];
    float ax = 0.f, ay = 0.f, az = 0.f, aw = 0.f;

    int j = s0;
    for (; j + 8 <= s1; j += 8) {
        int i0 = __builtin_nontemporal_load(csr + j + 0);
        int i1 = __builtin_nontemporal_load(csr + j + 1);
        int i2 = __builtin_nontemporal_load(csr + j + 2);
        int i3 = __builtin_nontemporal_load(csr + j + 3);
        int i4 = __builtin_nontemporal_load(csr + j + 4);
        int i5 = __builtin_nontemporal_load(csr + j + 5);
        int i6 = __builtin_nontemporal_load(csr + j + 6);
        int i7 = __builtin_nontemporal_load(csr + j + 7);
        if (act) {
            float4 v0 = *(const float4*)(Hs + (size_t)i0 * D + c);
            float4 v1 = *(const float4*)(Hs + (size_t)i1 * D + c);
            float4 v2 = *(const float4*)(Hs + (size_t)i2 * D + c);
            float4 v3 = *(const float4*)(Hs + (size_t)i3 * D + c);
            float4 v4 = *(const float4*)(Hs + (size_t)i4 * D + c);
            float4 v5 = *(const float4*)(Hs + (size_t)i5 * D + c);
            float4 v6 = *(const float4*)(Hs + (size_t)i6 * D + c);
            float4 v7 = *(const float4*)(Hs + (size_t)i7 * D + c);
            ax += v0.x; ay += v0.y; az += v0.z; aw += v0.w;
            ax += v1.x; ay += v1.y; az += v1.z; aw += v1.w;
            ax += v2.x; ay += v2.y; az += v2.z; aw += v2.w;
            ax += v3.x; ay += v3.y; az += v3.z; aw += v3.w;
            ax += v4.x; ay += v4.y; az += v4.z; aw += v4.w;
            ax += v5.x; ay += v5.y; az += v5.z; aw += v5.w;
            ax += v6.x; ay += v6.y; az += v6.z; aw += v6.w;
            ax += v7.x; ay += v7.y; az += v7.z; aw += v7.w;
        }
    }
    for (; j < s1; j++) {
        int s = __builtin_nontemporal_load(csr + j);
        if (act) {
            float4 v = *(const float4*)(Hs + (size_t)s * D + c);
            ax += v.x; ay += v.y; az += v.z; aw += v.w;
        }
    }

    float4 r = make_float4(0.f, 0.f, 0.f, 0.f);
    if (act) {
        float4 self = *(const float4*)(Hs + (size_t)node * D + c);
        float dn = dinv[node];
        float4 b4 = *(const float4*)(bias + c);
        r.x = (ax + self.x) * dn + b4.x;
        r.y = (ay + self.y) * dn + b4.y;
        r.z = (az + self.z) * dn + b4.z;
        r.w = (aw + self.w) * dn + b4.w;
    }

    float m = act ? fmaxf(fmaxf(r.x, r.y), fmaxf(r.z, r.w)) : -1e30f;
#pragma unroll
    for (int off = 8; off; off >>= 1) m = fmaxf(m, __shfl_xor(m, off, 16));
    float es = act ? (expf(r.x - m) + expf(r.y - m) + expf(r.z - m) + expf(r.w - m)) : 0.f;
#pragma unroll
    for (int off = 8; off; off >>= 1) es += __shfl_xor(es, off, 16);
    float ls = logf(es);
    if (act) {
        float4 o = make_float4(r.x - m - ls, r.y - m - ls, r.z - m - ls, r.w - m - ls);
        *(float4*)(out + (size_t)node * D + c) = o;
    }
}

// ---------------- BatchNorm stats (fp16 input) ----------------

__global__ __launch_bounds__(256) void k_bn_stats_h(const __half* __restrict__ H, float* __restrict__ sums, int N) {
    __shared__ float ls[256], ls2[256];
    int c = threadIdx.x & 127;
    int half = threadIdx.x >> 7;
    float s = 0.f, s2 = 0.f;
    for (int r = blockIdx.x * 2 + half; r < N; r += gridDim.x * 2) {
        float v = __half2float(H[(size_t)r * 128 + c]);
        s += v; s2 += v * v;
    }
    ls[threadIdx.x] = s; ls2[threadIdx.x] = s2;
    __syncthreads();
    if (threadIdx.x < 128) {
        atomicAdd(&sums[c], ls[threadIdx.x] + ls[threadIdx.x + 128]);
        atomicAdd(&sums[128 + c], ls2[threadIdx.x] + ls2[threadIdx.x + 128]);
    }
}

// ---------------- launch ----------------

extern "C" void kernel_launch(void* const* d_in, const int* in_sizes, int n_in,
                              void* d_out, int out_size, void* d_ws, size_t ws_size,
                              hipStream_t stream) {
    const float* x   = (const float*)d_in[0];
    const int*   ei  = (const int*)d_in[1];
    const float* W0  = (const float*)d_in[2];
    const float* b0  = (const float*)d_in[3];
    const float* W1  = (const float*)d_in[4];
    const float* b1  = (const float*)d_in[5];
    const float* W2  = (const float*)d_in[6];
    const float* b2  = (const float*)d_in[7];
    const float* g0  = (const float*)d_in[8];
    const float* bt0 = (const float*)d_in[9];
    const float* g1  = (const float*)d_in[10];
    const float* bt1 = (const float*)d_in[11];
    float* out = (float*)d_out;

    int N    = in_sizes[0] / 128;
    int E    = in_sizes[1] / 2;
    int DOUT = in_sizes[7];          // 40
    float invN = 1.0f / (float)N;

    const int* srcp = ei;
    const int* dstp = ei + E;

    size_t off = 0;
    auto carve = [&](size_t bytes) { size_t o = off; off += (bytes + 255) & ~(size_t)255; return (char*)d_ws + o; };
    // zero-group (one memset): cnt, cursor, stats0, stats1
    int*    cnt      = (int*)carve((size_t)N * 4);
    int*    cursor   = (int*)carve((size_t)N * 4);
    float*  stats0   = (float*)carve(256 * 4);
    float*  stats1   = (float*)carve(256 * 4);
    size_t zero_span = (size_t)((char*)stats1 + 256 * 4 - (char*)cnt);
    int*    rowstart = (int*)carve((size_t)(N + 1) * 4);
    int*    csr      = (int*)carve((size_t)E * 4);
    float*  dinv     = (float*)carve((size_t)N * 4);
    int*    bsum     = (int*)carve(64 * 4);
    __half* W0t      = (__half*)carve(128 * 128 * 2);
    __half* W1t      = (__half*)carve(128 * 128 * 2);
    __half* W2t      = (__half*)carve(48 * 128 * 2);
    __half* HgH      = (__half*)carve((size_t)N * 128 * 2);
    __half* HaH      = (__half*)carve((size_t)N * 128 * 2);
    float*  Hg32     = (float*)carve((size_t)N * 40 * 4);

    hipMemsetAsync(cnt, 0, zero_span, stream);

    int SB = (N + 4095) / 4096;
    int WTB = (32768 + 48 * 128 + 255) / 256;       // weight-transpose blocks
    int EB  = (E + 255) / 256;                      // edge blocks
    int gemm_blocks = (N + 63) / 64;
    int aggH_blocks = (N + 7) / 8;
    int aggO_blocks = (N + 15) / 16;

    // [weight transpose || degree count]
    k_wt_count<<<WTB + EB, 256, 0, stream>>>(W0, W1, W2, W0t, W1t, W2t, DOUT, dstp, cnt, E, WTB);
    k_scan_sum<<<SB, 256, 0, stream>>>(cnt, bsum, N);
    k_scan_apply<<<SB, 256, 0, stream>>>(cnt, bsum, rowstart, dinv, N, SB);

    // [layer-1 GEMM || CSR scatter]  (independent: gemm1 needs dinv; scatter needs rowstart)
    k_gemm1_scatter<<<gemm_blocks + EB, 256, 0, stream>>>(x, W0t, dinv, HgH, N, 128, gemm_blocks,
                                                          srcp, dstp, rowstart, cursor, csr, E);

    // layer 1 aggregate + stats
    k_aggregate_h<<<aggH_blocks, 256, 0, stream>>>(HgH, csr, rowstart, dinv, b0, HaH, N);
    k_bn_stats_h<<<512, 256, 0, stream>>>(HaH, stats0, N);

    // layer 2 (BN0+ReLU fused into A-fragment, from raw sums)
    k_gemm_mfma<8, __half, __half><<<gemm_blocks, 256, 0, stream>>>(HaH, W1t, stats0, g0, bt0, invN, dinv, HgH, N, 128);
    k_aggregate_h<<<aggH_blocks, 256, 0, stream>>>(HgH, csr, rowstart, dinv, b1, HaH, N);
    k_bn_stats_h<<<512, 256, 0, stream>>>(HaH, stats1, N);

    // layer 3 (BN1+ReLU fused; fp32 out; aggregate fused with log_softmax)
    k_gemm_mfma<3, __half, float><<<gemm_blocks, 256, 0, stream>>>(HaH, W2t, stats1, g1, bt1, invN, dinv, Hg32, N, DOUT);
    k_aggregate_lsm<<<aggO_blocks, 256, 0, stream>>>(Hg32, csr, rowstart, dinv, b2, out, N, DOUT);
}